// Round 2
// baseline (1077.907 us; speedup 1.0000x reference)
//
#include <hip/hip_runtime.h>
#include <hip/hip_bf16.h>
#include <stdint.h>

#define S_TOK 32768
#define M_DIM 512
#define E_NUM 64
#define V_DIM 2048
#define CAP   1024

typedef __attribute__((ext_vector_type(8))) short short8;
typedef __attribute__((ext_vector_type(4))) float f32x4;

__device__ __forceinline__ unsigned short f2bf(float f) {
  unsigned int u = __float_as_uint(f);
  unsigned int r = (u + 0x7fffu + ((u >> 16) & 1u)) >> 16;
  return (unsigned short)r;
}
__device__ __forceinline__ float bf2f(unsigned short h) {
  return __uint_as_float(((unsigned int)h) << 16);
}

__device__ __forceinline__ void gload16(const void* g, void* lds) {
  __builtin_amdgcn_global_load_lds(
      (const __attribute__((address_space(1))) void*)g,
      (__attribute__((address_space(3))) void*)lds, 16, 0, 0);
}

// ---------------- x fp32 -> bf16 ----------------
__global__ __launch_bounds__(256) void convert_x_kernel(const float* __restrict__ in,
                                                        unsigned short* __restrict__ out) {
  int i = blockIdx.x * 256 + threadIdx.x;
  float4 v = reinterpret_cast<const float4*>(in)[i];
  ushort4 o;
  o.x = f2bf(v.x); o.y = f2bf(v.y); o.z = f2bf(v.z); o.w = f2bf(v.w);
  reinterpret_cast<ushort4*>(out)[i] = o;
}

// ------------- weight transpose + convert: [b][R][Cc] f32 -> [b][Cc][R] bf16 -------------
__global__ __launch_bounds__(256) void transpose_convert(const float* __restrict__ in,
                                                         unsigned short* __restrict__ out,
                                                         int R, int Cc) {
  __shared__ float tile[32][33];
  int b = blockIdx.z;
  const float* ip = in + (size_t)b * R * Cc;
  unsigned short* op = out + (size_t)b * R * Cc;
  int c0 = blockIdx.x * 32, r0 = blockIdx.y * 32;
  int tx = threadIdx.x & 31, ty = threadIdx.x >> 5;  // ty: 0..7
  #pragma unroll
  for (int j = 0; j < 32; j += 8)
    tile[ty + j][tx] = ip[(size_t)(r0 + ty + j) * Cc + c0 + tx];
  __syncthreads();
  int tid = threadIdx.x;
  #pragma unroll
  for (int j = 0; j < 32; j += 16) {
    int c = (tid >> 4) + j;       // col within tile 0..31
    int r2 = (tid & 15) * 2;      // row pair
    ushort2 o;
    o.x = f2bf(tile[r2][c]);
    o.y = f2bf(tile[r2 + 1][c]);
    *reinterpret_cast<ushort2*>(&op[(size_t)(c0 + c) * R + r0 + r2]) = o;
  }
}

// ---------------- gating: logits, softmax, top-2, partial me/ce ----------------
__global__ __launch_bounds__(256) void gating_kernel(
    const float* __restrict__ x, const float* __restrict__ wg,
    int* __restrict__ topk, float* __restrict__ gates_n,
    float* __restrict__ me_part, int* __restrict__ ce_part) {
  __shared__ float4 xs4[16 * 128];
  __shared__ float mered[4][64];
  __shared__ int cered[4][64];
  int tid = threadIdx.x;
  int l = tid & 63, w = tid >> 6;
  int tb = blockIdx.x * 16;
  const float4* xg4 = reinterpret_cast<const float4*>(x) + (size_t)tb * 128;
  #pragma unroll
  for (int i = 0; i < 8; ++i) xs4[i * 256 + tid] = xg4[i * 256 + tid];
  __syncthreads();

  const float4* wg4 = reinterpret_cast<const float4*>(wg) + (size_t)l * 128;
  float acc[4] = {0.f, 0.f, 0.f, 0.f};
  for (int i = 0; i < 128; ++i) {
    float4 wv = wg4[i];
    #pragma unroll
    for (int t = 0; t < 4; ++t) {
      float4 xv = xs4[(w * 4 + t) * 128 + i];
      acc[t] += xv.x * wv.x; acc[t] += xv.y * wv.y;
      acc[t] += xv.z * wv.z; acc[t] += xv.w * wv.w;
    }
  }

  float melocal = 0.f;
  int celocal = 0;
  for (int t = 0; t < 4; ++t) {
    float v = acc[t];
    // top-1 (lower index wins ties, matching lax.top_k)
    float bv = v; int bi = l;
    #pragma unroll
    for (int off = 32; off; off >>= 1) {
      float ov = __shfl_xor(bv, off);
      int oi = __shfl_xor(bi, off);
      if (ov > bv || (ov == bv && oi < bi)) { bv = ov; bi = oi; }
    }
    // top-2
    float v2 = (l == bi) ? -INFINITY : v;
    float bv2 = v2; int bi2 = l;
    #pragma unroll
    for (int off = 32; off; off >>= 1) {
      float ov = __shfl_xor(bv2, off);
      int oi = __shfl_xor(bi2, off);
      if (ov > bv2 || (ov == bv2 && oi < bi2)) { bv2 = ov; bi2 = oi; }
    }
    float ex = expf(v - bv);
    float s = ex;
    #pragma unroll
    for (int off = 32; off; off >>= 1) s += __shfl_xor(s, off);
    melocal += ex / s;
    if (l == bi) celocal += 1;
    if (l == 0) {
      int sidx = tb + w * 4 + t;
      topk[sidx * 2 + 0] = bi;
      topk[sidx * 2 + 1] = bi2;
      float g1 = 1.0f / s;                 // exp(bv-bv)/s
      float g2 = expf(bv2 - bv) / s;
      float denom = fmaxf(g1 + g2, 1.1920929e-07f);
      gates_n[sidx * 2 + 0] = g1 / denom;
      gates_n[sidx * 2 + 1] = g2 / denom;
    }
  }
  mered[w][l] = melocal;
  cered[w][l] = celocal;
  __syncthreads();
  if (tid < 64) {
    me_part[blockIdx.x * 64 + tid] =
        mered[0][tid] + mered[1][tid] + mered[2][tid] + mered[3][tid];
    ce_part[blockIdx.x * 64 + tid] =
        cered[0][tid] + cered[1][tid] + cered[2][tid] + cered[3][tid];
  }
}

// ---------------- per-expert sequential ranking (capacity assignment) ----------------
__global__ __launch_bounds__(256) void rank_kernel(const int* __restrict__ topk,
                                                   int* __restrict__ dest,
                                                   int* __restrict__ slot_map) {
  int e = blockIdx.x;
  int tid = threadIdx.x;
  int l = tid & 63, w = tid >> 6;
  __shared__ int wtot[4];
  int base = 0;  // after k=0 loop, base == n0[e] (uncapped), which offsets k=1
  for (int k = 0; k < 2; ++k) {
    for (int c0 = 0; c0 < S_TOK; c0 += 256) {
      int s = c0 + tid;
      int choice = topk[s * 2 + k];
      bool m = (choice == e);
      unsigned long long mask = __ballot(m);
      if (l == 0) wtot[w] = __popcll(mask);
      __syncthreads();
      int offw = 0;
      #pragma unroll
      for (int j = 0; j < 4; ++j)
        if (j < w) offw += wtot[j];
      int tot = wtot[0] + wtot[1] + wtot[2] + wtot[3];
      if (m) {
        int pre = __popcll(mask & ((1ull << l) - 1ull));
        int loc = base + offw + pre;
        int d = (loc < CAP) ? (e * CAP + loc) : -1;
        dest[s * 2 + k] = d;
        if (d >= 0) slot_map[d] = s;
      }
      base += tot;
      __syncthreads();
    }
  }
}

// ---------------- bf16 MFMA GEMM, m97 structure (128x128 tile, BK=64) ----------------
// A: row-major [rows][KD] bf16 (GATHER: rows via slot_map from xbf)
// BT: [E][ND][KD] bf16 (B transposed, K contiguous)
// out: [E*CAP][ND] bf16 = act(A@B + bias)
template <int KD, int ND, bool GATHER, bool RELU>
__global__ __launch_bounds__(256) void gemm_kernel(
    const unsigned short* __restrict__ A,
    const unsigned short* __restrict__ BT,
    const float* __restrict__ bias,
    const int* __restrict__ slot_map,
    unsigned short* __restrict__ out) {
  __shared__ __align__(16) unsigned short As[128 * 64];
  __shared__ __align__(16) unsigned short Bs[128 * 64];
  int tid = threadIdx.x;
  int l = tid & 63;
  int w = tid >> 6;
  int e = blockIdx.z;
  int n0 = blockIdx.x * 128;
  int r0 = blockIdx.y * 128;

  const unsigned short* asrc[4];
  const unsigned short* bsrc[4];
  unsigned short* adst[4];
  unsigned short* bdst[4];
  #pragma unroll
  for (int i = 0; i < 4; ++i) {
    int chunk = i * 256 + tid;
    int row = chunk >> 3, kc = chunk & 7;
    if (GATHER) {
      int s = slot_map[e * CAP + r0 + row];
      if (s < 0) s = 0;  // unfilled slot: load any valid row; output never read
      asrc[i] = A + (size_t)s * KD + kc * 8;
    } else {
      asrc[i] = A + ((size_t)(e * CAP + r0 + row)) * KD + kc * 8;
    }
    bsrc[i] = BT + ((size_t)e * ND + n0 + row) * KD + kc * 8;
    adst[i] = &As[chunk * 8];
    bdst[i] = &Bs[chunk * 8];
  }

  int wrow = (w >> 1) * 64;
  int wcol = (w & 1) * 64;
  int lr = l & 15;
  int lk = (l >> 4) * 8;

  f32x4 acc[4][4];
  f32x4 zero = {0.f, 0.f, 0.f, 0.f};
  #pragma unroll
  for (int m = 0; m < 4; ++m)
    #pragma unroll
    for (int n = 0; n < 4; ++n) acc[m][n] = zero;

  for (int kt = 0; kt < KD / 64; ++kt) {
    #pragma unroll
    for (int i = 0; i < 4; ++i) {
      gload16(asrc[i] + kt * 64, adst[i]);
      gload16(bsrc[i] + kt * 64, bdst[i]);
    }
    __syncthreads();
    #pragma unroll
    for (int ks = 0; ks < 2; ++ks) {
      short8 a[4], b[4];
      #pragma unroll
      for (int m = 0; m < 4; ++m)
        a[m] = *reinterpret_cast<const short8*>(
            &As[(wrow + m * 16 + lr) * 64 + ks * 32 + lk]);
      #pragma unroll
      for (int n = 0; n < 4; ++n)
        b[n] = *reinterpret_cast<const short8*>(
            &Bs[(wcol + n * 16 + lr) * 64 + ks * 32 + lk]);
      #pragma unroll
      for (int m = 0; m < 4; ++m)
        #pragma unroll
        for (int n = 0; n < 4; ++n)
          acc[m][n] = __builtin_amdgcn_mfma_f32_16x16x32_bf16(a[m], b[n], acc[m][n], 0, 0, 0);
    }
    __syncthreads();
  }

  #pragma unroll
  for (int n = 0; n < 4; ++n) {
    int gc = n0 + wcol + n * 16 + lr;
    float bv = bias[e * ND + gc];
    #pragma unroll
    for (int m = 0; m < 4; ++m) {
      int gr = r0 + wrow + m * 16 + (l >> 4) * 4;
      #pragma unroll
      for (int j = 0; j < 4; ++j) {
        float v = acc[m][n][j] + bv;
        if (RELU) v = fmaxf(v, 0.f);
        out[((size_t)(e * CAP + gr + j)) * ND + gc] = f2bf(v);
      }
    }
  }
}

// ---------------- decode: y[s] = g1*valid1*Y[d1] + g2*valid2*Y[d2] ----------------
__global__ __launch_bounds__(256) void decode_kernel(
    const unsigned short* __restrict__ Y, const int* __restrict__ dest,
    const float* __restrict__ gn, float* __restrict__ y) {
  int t = blockIdx.x * 4 + (threadIdx.x >> 6);
  int m0 = (threadIdx.x & 63) * 8;
  int d0 = dest[t * 2 + 0], d1 = dest[t * 2 + 1];
  float g0 = gn[t * 2 + 0], g1 = gn[t * 2 + 1];
  float o[8];
  #pragma unroll
  for (int j = 0; j < 8; ++j) o[j] = 0.f;
  if (d0 >= 0) {
    short8 v = *reinterpret_cast<const short8*>(&Y[(size_t)d0 * M_DIM + m0]);
    #pragma unroll
    for (int j = 0; j < 8; ++j) o[j] += g0 * bf2f((unsigned short)v[j]);
  }
  if (d1 >= 0) {
    short8 v = *reinterpret_cast<const short8*>(&Y[(size_t)d1 * M_DIM + m0]);
    #pragma unroll
    for (int j = 0; j < 8; ++j) o[j] += g1 * bf2f((unsigned short)v[j]);
  }
  float4 o0 = {o[0], o[1], o[2], o[3]};
  float4 o1 = {o[4], o[5], o[6], o[7]};
  *reinterpret_cast<float4*>(&y[(size_t)t * M_DIM + m0]) = o0;
  *reinterpret_cast<float4*>(&y[(size_t)t * M_DIM + m0 + 4]) = o1;
}

// ---------------- aux loss ----------------
__global__ void loss_kernel(const float* __restrict__ me_part,
                            const int* __restrict__ ce_part,
                            float* __restrict__ out) {
  int e = threadIdx.x;  // 64 threads
  float sme = 0.f, sce = 0.f;
  for (int b = 0; b < S_TOK / 16; ++b) {
    sme += me_part[b * 64 + e];
    sce += (float)ce_part[b * 64 + e];
  }
  float p = sme * sce;
  #pragma unroll
  for (int off = 32; off; off >>= 1) p += __shfl_xor(p, off);
  if (e == 0) out[0] = p * ((float)E_NUM / ((float)S_TOK * (float)S_TOK));
}

extern "C" void kernel_launch(void* const* d_in, const int* in_sizes, int n_in,
                              void* d_out, int out_size, void* d_ws, size_t ws_size,
                              hipStream_t stream) {
  const float* x     = (const float*)d_in[0];
  const float* wg    = (const float*)d_in[1];
  const float* fc1_w = (const float*)d_in[2];
  const float* fc1_b = (const float*)d_in[3];
  const float* fc2_w = (const float*)d_in[4];
  const float* fc2_b = (const float*)d_in[5];
  float* y = (float*)d_out;
  float* loss_out = y + (size_t)S_TOK * M_DIM;

  char* ws = (char*)d_ws;
  size_t off = 0;
  auto alloc = [&](size_t bytes) {
    char* p = ws + off;
    off += (bytes + 255) & ~(size_t)255;
    return p;
  };
  unsigned short* wT1 = (unsigned short*)alloc((size_t)E_NUM * V_DIM * M_DIM * 2);  // 128 MB
  unsigned short* wT2 = (unsigned short*)alloc((size_t)E_NUM * M_DIM * V_DIM * 2);  // 128 MB
  unsigned short* H   = (unsigned short*)alloc((size_t)E_NUM * CAP * V_DIM * 2);    // 256 MB
  unsigned short* xbf = (unsigned short*)alloc((size_t)S_TOK * M_DIM * 2);          // 32 MB
  int*   topk     = (int*)alloc((size_t)S_TOK * 2 * 4);
  float* gatesn   = (float*)alloc((size_t)S_TOK * 2 * 4);
  int*   dest     = (int*)alloc((size_t)S_TOK * 2 * 4);
  int*   slot_map = (int*)alloc((size_t)E_NUM * CAP * 4);
  float* me_part  = (float*)alloc((size_t)(S_TOK / 16) * 64 * 4);
  int*   ce_part  = (int*)alloc((size_t)(S_TOK / 16) * 64 * 4);
  // Y aliases wT1 (wT1 is dead after gemm1; gemm2 writes Y, reads wT2+H)
  unsigned short* Y = wT1;

  (void)hipMemsetAsync(slot_map, 0xFF, (size_t)E_NUM * CAP * 4, stream);

  convert_x_kernel<<<S_TOK * M_DIM / 4 / 256, 256, 0, stream>>>(x, xbf);
  // fc1_w [E][M][V] -> wT1 [E][V][M]
  transpose_convert<<<dim3(V_DIM / 32, M_DIM / 32, E_NUM), 256, 0, stream>>>(fc1_w, wT1, M_DIM, V_DIM);
  // fc2_w [E][V][M] -> wT2 [E][M][V]
  transpose_convert<<<dim3(M_DIM / 32, V_DIM / 32, E_NUM), 256, 0, stream>>>(fc2_w, wT2, V_DIM, M_DIM);

  gating_kernel<<<S_TOK / 16, 256, 0, stream>>>(x, wg, topk, gatesn, me_part, ce_part);
  rank_kernel<<<E_NUM, 256, 0, stream>>>(topk, dest, slot_map);

  // H = relu(gather(x) @ fc1 + b1)
  gemm_kernel<512, 2048, true, true>
      <<<dim3(V_DIM / 128, CAP / 128, E_NUM), 256, 0, stream>>>(xbf, wT1, fc1_b, slot_map, H);
  // Y = H @ fc2 + b2
  gemm_kernel<2048, 512, false, false>
      <<<dim3(M_DIM / 128, CAP / 128, E_NUM), 256, 0, stream>>>(H, wT2, fc2_b, slot_map, Y);

  decode_kernel<<<S_TOK / 4, 256, 0, stream>>>(Y, dest, gatesn, y);
  loss_kernel<<<1, 64, 0, stream>>>(me_part, ce_part, loss_out);
}

// Round 3
// 989.108 us; speedup vs baseline: 1.0898x; 1.0898x over previous
//
#include <hip/hip_runtime.h>
#include <hip/hip_bf16.h>
#include <stdint.h>

#define S_TOK 32768
#define M_DIM 512
#define E_NUM 64
#define V_DIM 2048
#define CAP   1024

typedef __attribute__((ext_vector_type(8))) short short8;
typedef __attribute__((ext_vector_type(4))) float f32x4;

__device__ __forceinline__ unsigned short f2bf(float f) {
  unsigned int u = __float_as_uint(f);
  unsigned int r = (u + 0x7fffu + ((u >> 16) & 1u)) >> 16;
  return (unsigned short)r;
}
__device__ __forceinline__ float bf2f(unsigned short h) {
  return __uint_as_float(((unsigned int)h) << 16);
}

__device__ __forceinline__ void gload16(const void* g, void* lds) {
  __builtin_amdgcn_global_load_lds(
      (const __attribute__((address_space(1))) void*)g,
      (__attribute__((address_space(3))) void*)lds, 16, 0, 0);
}

// ---------------- x fp32 -> bf16 ----------------
__global__ __launch_bounds__(256) void convert_x_kernel(const float* __restrict__ in,
                                                        unsigned short* __restrict__ out) {
  int i = blockIdx.x * 256 + threadIdx.x;
  float4 v = reinterpret_cast<const float4*>(in)[i];
  ushort4 o;
  o.x = f2bf(v.x); o.y = f2bf(v.y); o.z = f2bf(v.z); o.w = f2bf(v.w);
  reinterpret_cast<ushort4*>(out)[i] = o;
}

// ------------- weight transpose + convert: [b][R][Cc] f32 -> [b][Cc][R] bf16 -------------
__global__ __launch_bounds__(256) void transpose_convert(const float* __restrict__ in,
                                                         unsigned short* __restrict__ out,
                                                         int R, int Cc) {
  __shared__ float tile[32][33];
  int b = blockIdx.z;
  const float* ip = in + (size_t)b * R * Cc;
  unsigned short* op = out + (size_t)b * R * Cc;
  int c0 = blockIdx.x * 32, r0 = blockIdx.y * 32;
  int tx = threadIdx.x & 31, ty = threadIdx.x >> 5;  // ty: 0..7
  #pragma unroll
  for (int j = 0; j < 32; j += 8)
    tile[ty + j][tx] = ip[(size_t)(r0 + ty + j) * Cc + c0 + tx];
  __syncthreads();
  int tid = threadIdx.x;
  #pragma unroll
  for (int j = 0; j < 32; j += 16) {
    int c = (tid >> 4) + j;       // col within tile 0..31
    int r2 = (tid & 15) * 2;      // row pair
    ushort2 o;
    o.x = f2bf(tile[r2][c]);
    o.y = f2bf(tile[r2 + 1][c]);
    *reinterpret_cast<ushort2*>(&op[(size_t)(c0 + c) * R + r0 + r2]) = o;
  }
}

// ---------------- gating: logits, softmax, top-2, partial me/ce ----------------
__global__ __launch_bounds__(256) void gating_kernel(
    const float* __restrict__ x, const float* __restrict__ wg,
    int* __restrict__ topk, float* __restrict__ gates_n,
    float* __restrict__ me_part, int* __restrict__ ce_part) {
  __shared__ float4 xs4[16 * 128];
  __shared__ float mered[4][64];
  __shared__ int cered[4][64];
  int tid = threadIdx.x;
  int l = tid & 63, w = tid >> 6;
  int tb = blockIdx.x * 16;
  const float4* xg4 = reinterpret_cast<const float4*>(x) + (size_t)tb * 128;
  #pragma unroll
  for (int i = 0; i < 8; ++i) xs4[i * 256 + tid] = xg4[i * 256 + tid];
  __syncthreads();

  const float4* wg4 = reinterpret_cast<const float4*>(wg) + (size_t)l * 128;
  float acc[4] = {0.f, 0.f, 0.f, 0.f};
  for (int i = 0; i < 128; ++i) {
    float4 wv = wg4[i];
    #pragma unroll
    for (int t = 0; t < 4; ++t) {
      float4 xv = xs4[(w * 4 + t) * 128 + i];
      acc[t] += xv.x * wv.x; acc[t] += xv.y * wv.y;
      acc[t] += xv.z * wv.z; acc[t] += xv.w * wv.w;
    }
  }

  float melocal = 0.f;
  int celocal = 0;
  for (int t = 0; t < 4; ++t) {
    float v = acc[t];
    float bv = v; int bi = l;
    #pragma unroll
    for (int off = 32; off; off >>= 1) {
      float ov = __shfl_xor(bv, off);
      int oi = __shfl_xor(bi, off);
      if (ov > bv || (ov == bv && oi < bi)) { bv = ov; bi = oi; }
    }
    float v2 = (l == bi) ? -INFINITY : v;
    float bv2 = v2; int bi2 = l;
    #pragma unroll
    for (int off = 32; off; off >>= 1) {
      float ov = __shfl_xor(bv2, off);
      int oi = __shfl_xor(bi2, off);
      if (ov > bv2 || (ov == bv2 && oi < bi2)) { bv2 = ov; bi2 = oi; }
    }
    float ex = expf(v - bv);
    float s = ex;
    #pragma unroll
    for (int off = 32; off; off >>= 1) s += __shfl_xor(s, off);
    melocal += ex / s;
    if (l == bi) celocal += 1;
    if (l == 0) {
      int sidx = tb + w * 4 + t;
      topk[sidx * 2 + 0] = bi;
      topk[sidx * 2 + 1] = bi2;
      float g1 = 1.0f / s;
      float g2 = expf(bv2 - bv) / s;
      float denom = fmaxf(g1 + g2, 1.1920929e-07f);
      gates_n[sidx * 2 + 0] = g1 / denom;
      gates_n[sidx * 2 + 1] = g2 / denom;
    }
  }
  mered[w][l] = melocal;
  cered[w][l] = celocal;
  __syncthreads();
  if (tid < 64) {
    me_part[blockIdx.x * 64 + tid] =
        mered[0][tid] + mered[1][tid] + mered[2][tid] + mered[3][tid];
    ce_part[blockIdx.x * 64 + tid] =
        cered[0][tid] + cered[1][tid] + cered[2][tid] + cered[3][tid];
  }
}

// ---------------- per-expert sequential ranking (capacity assignment) ----------------
__global__ __launch_bounds__(256) void rank_kernel(const int* __restrict__ topk,
                                                   int* __restrict__ dest,
                                                   int* __restrict__ slot_map) {
  int e = blockIdx.x;
  int tid = threadIdx.x;
  int l = tid & 63, w = tid >> 6;
  __shared__ int wtot[4];
  int base = 0;  // after k=0 loop, base == n0[e] (uncapped), which offsets k=1
  for (int k = 0; k < 2; ++k) {
    for (int c0 = 0; c0 < S_TOK; c0 += 256) {
      int s = c0 + tid;
      int choice = topk[s * 2 + k];
      bool m = (choice == e);
      unsigned long long mask = __ballot(m);
      if (l == 0) wtot[w] = __popcll(mask);
      __syncthreads();
      int offw = 0;
      #pragma unroll
      for (int j = 0; j < 4; ++j)
        if (j < w) offw += wtot[j];
      int tot = wtot[0] + wtot[1] + wtot[2] + wtot[3];
      if (m) {
        int pre = __popcll(mask & ((1ull << l) - 1ull));
        int loc = base + offw + pre;
        int d = (loc < CAP) ? (e * CAP + loc) : -1;
        dest[s * 2 + k] = d;
        if (d >= 0) slot_map[d] = s;
      }
      base += tot;
      __syncthreads();
    }
  }
}

// =================== 256x256 8-phase MFMA GEMM (T2+T3+T4+T5) ===================
// A: row-major [rows][KD] bf16 (GATHER: rows via slot_map)
// BT: [E][ND][KD] bf16; out: [E*CAP][ND] bf16 = act(A@B + bias)
// 8 waves (2M x 4N), per-wave 128x64 out, BK=64, dbuf LDS 128 KiB, XOR swizzle.
#define PH_TOP                                                                 \
  __builtin_amdgcn_sched_barrier(0);                                           \
  __builtin_amdgcn_s_barrier();                                                \
  asm volatile("s_waitcnt lgkmcnt(0)" ::: "memory");                           \
  __builtin_amdgcn_sched_barrier(0);                                           \
  __builtin_amdgcn_s_setprio(1);
#define PH_BOT                                                                 \
  __builtin_amdgcn_s_setprio(0);                                               \
  __builtin_amdgcn_sched_barrier(0);                                           \
  __builtin_amdgcn_s_barrier();

template <int KD, int ND, int NBX, int NBY, bool GATHER, bool RELU>
__global__ __launch_bounds__(512, 2) void gemm8_kernel(
    const unsigned short* __restrict__ A,
    const unsigned short* __restrict__ BT,
    const float* __restrict__ bias,
    const int* __restrict__ slot_map,
    unsigned short* __restrict__ out) {
  constexpr int NT = KD / 64;  // K-tiles
  __shared__ __align__(16) unsigned short Asl[2][256 * 64];
  __shared__ __align__(16) unsigned short Bsl[2][256 * 64];

  const int tid = threadIdx.x;
  const int l = tid & 63;
  const int w = tid >> 6;       // 0..7
  const int wm = w >> 2;        // 0..1
  const int wn = w & 3;         // 0..3
  const int lr = l & 15;
  const int lk8 = l >> 4;       // 0..3

  // XCD-chunked bijective block swizzle (nwg % 8 == 0)
  const int nwg = E_NUM * NBX * NBY;
  const int cpx = nwg >> 3;
  int lid = ((int)blockIdx.x % 8) * cpx + (int)blockIdx.x / 8;
  const int e = lid / (NBX * NBY);
  int rem = lid % (NBX * NBY);
  const int n0 = (rem / NBY) * 256;
  const int r0 = (rem % NBY) * 256;

  // stage swizzle: LDS group (l&7) at row r holds global colgroup (l&7)^(r&7)
  const int cg8 = (((l & 7) ^ (l >> 3)) * 8);

  // per-thread precomputed stage offsets (elements) and LDS dests
  uint32_t offA[2][2], offB[2][2], ldsA[2][2], ldsB[2][2];
  #pragma unroll
  for (int sel = 0; sel < 2; ++sel) {
    #pragma unroll
    for (int i = 0; i < 2; ++i) {
      int lr128 = i * 64 + w * 8 + (l >> 3);
      int ar = ((lr128 >> 6) * 128) + sel * 64 + (lr128 & 63);
      int br = ((lr128 >> 5) * 64) + sel * 32 + (lr128 & 31);
      ldsA[sel][i] = ar * 64 + (l & 7) * 8;
      ldsB[sel][i] = br * 64 + (l & 7) * 8;
      int arow;
      if (GATHER) {
        int s = slot_map[e * CAP + r0 + ar];
        if (s < 0) s = 0;  // unfilled slot: any valid row; output never read
        arow = s;
      } else {
        arow = e * CAP + r0 + ar;
      }
      offA[sel][i] = (uint32_t)arow * KD + cg8;
      offB[sel][i] = (uint32_t)(n0 + br) * KD + cg8;
    }
  }
  const unsigned short* Bexp = BT + (size_t)e * ND * KD;

#define STAGE_A(sel, p, kt)                                                    \
  do {                                                                         \
    gload16(A + offA[sel][0] + (kt) * 64, &Asl[p][ldsA[sel][0]]);              \
    gload16(A + offA[sel][1] + (kt) * 64, &Asl[p][ldsA[sel][1]]);              \
  } while (0)
#define STAGE_B(sel, p, kt)                                                    \
  do {                                                                         \
    gload16(Bexp + offB[sel][0] + (kt) * 64, &Bsl[p][ldsB[sel][0]]);           \
    gload16(Bexp + offB[sel][1] + (kt) * 64, &Bsl[p][ldsB[sel][1]]);           \
  } while (0)

  // fragment-read swizzled col offsets (elements)
  const int sg0 = ((0 + lk8) ^ (lr & 7)) * 8;
  const int sg1 = ((4 + lk8) ^ (lr & 7)) * 8;
#define RD_A(p, mh, mi, ks)                                                    \
  (*reinterpret_cast<const short8*>(                                           \
      &Asl[p][(wm * 128 + (mh) * 64 + (mi) * 16 + lr) * 64 + ((ks) ? sg1 : sg0)]))
#define RD_B(p, nh, ni, ks)                                                    \
  (*reinterpret_cast<const short8*>(                                           \
      &Bsl[p][(wn * 64 + (nh) * 32 + (ni) * 16 + lr) * 64 + ((ks) ? sg1 : sg0)]))

  short8 afr[2][4][2];  // [mh][mi][ks]
  short8 bfr[2][2];     // [ni][ks], current nh
  f32x4 acc[8][4];
  f32x4 zero = {0.f, 0.f, 0.f, 0.f};
  #pragma unroll
  for (int m = 0; m < 8; ++m)
    #pragma unroll
    for (int n = 0; n < 4; ++n) acc[m][n] = zero;

  // prologue: tile0 complete + tile1 {Amh0, Amh1, Bnh0}  (14 vmem ops)
  STAGE_A(0, 0, 0); STAGE_A(1, 0, 0); STAGE_B(0, 0, 0); STAGE_B(1, 0, 0);
  STAGE_A(0, 1, 1); STAGE_A(1, 1, 1); STAGE_B(0, 1, 1);
  asm volatile("s_waitcnt vmcnt(6)" ::: "memory");  // tile0's 8 ops complete
  __builtin_amdgcn_sched_barrier(0);
  __builtin_amdgcn_s_barrier();

#define GROUP(k, p)                                                            \
  {                                                                            \
    /* ---- phase 1: quadrant (mh0, nh0); stage Bnh1(k+1) -> dbuf[p^1] */      \
    _Pragma("unroll") for (int mi = 0; mi < 4; ++mi) {                         \
      afr[0][mi][0] = RD_A(p, 0, mi, 0);                                       \
      afr[0][mi][1] = RD_A(p, 0, mi, 1);                                       \
    }                                                                          \
    _Pragma("unroll") for (int ni = 0; ni < 2; ++ni) {                         \
      bfr[ni][0] = RD_B(p, 0, ni, 0);                                          \
      bfr[ni][1] = RD_B(p, 0, ni, 1);                                          \
    }                                                                          \
    if ((k) + 1 < NT) { STAGE_B(1, (p) ^ 1, (k) + 1); }                        \
    PH_TOP                                                                     \
    _Pragma("unroll") for (int mi = 0; mi < 4; ++mi)                           \
      _Pragma("unroll") for (int ni = 0; ni < 2; ++ni) {                       \
        acc[mi][ni] = __builtin_amdgcn_mfma_f32_16x16x32_bf16(                 \
            afr[0][mi][0], bfr[ni][0], acc[mi][ni], 0, 0, 0);                  \
        acc[mi][ni] = __builtin_amdgcn_mfma_f32_16x16x32_bf16(                 \
            afr[0][mi][1], bfr[ni][1], acc[mi][ni], 0, 0, 0);                  \
      }                                                                        \
    PH_BOT                                                                     \
    /* ---- phase 2: quadrant (mh1, nh0); stage Amh0(k+2) -> dbuf[p] */        \
    _Pragma("unroll") for (int mi = 0; mi < 4; ++mi) {                         \
      afr[1][mi][0] = RD_A(p, 1, mi, 0);                                       \
      afr[1][mi][1] = RD_A(p, 1, mi, 1);                                       \
    }                                                                          \
    if ((k) + 2 < NT) { STAGE_A(0, p, (k) + 2); }                              \
    PH_TOP                                                                     \
    _Pragma("unroll") for (int mi = 0; mi < 4; ++mi)                           \
      _Pragma("unroll") for (int ni = 0; ni < 2; ++ni) {                       \
        acc[4 + mi][ni] = __builtin_amdgcn_mfma_f32_16x16x32_bf16(             \
            afr[1][mi][0], bfr[ni][0], acc[4 + mi][ni], 0, 0, 0);              \
        acc[4 + mi][ni] = __builtin_amdgcn_mfma_f32_16x16x32_bf16(             \
            afr[1][mi][1], bfr[ni][1], acc[4 + mi][ni], 0, 0, 0);              \
      }                                                                        \
    PH_BOT                                                                     \
    /* ---- phase 3: quadrant (mh0, nh1); stage Amh1(k+2) -> dbuf[p] */        \
    _Pragma("unroll") for (int ni = 0; ni < 2; ++ni) {                         \
      bfr[ni][0] = RD_B(p, 1, ni, 0);                                          \
      bfr[ni][1] = RD_B(p, 1, ni, 1);                                          \
    }                                                                          \
    if ((k) + 2 < NT) { STAGE_A(1, p, (k) + 2); }                              \
    PH_TOP                                                                     \
    _Pragma("unroll") for (int mi = 0; mi < 4; ++mi)                           \
      _Pragma("unroll") for (int ni = 0; ni < 2; ++ni) {                       \
        acc[mi][2 + ni] = __builtin_amdgcn_mfma_f32_16x16x32_bf16(             \
            afr[0][mi][0], bfr[ni][0], acc[mi][2 + ni], 0, 0, 0);              \
        acc[mi][2 + ni] = __builtin_amdgcn_mfma_f32_16x16x32_bf16(             \
            afr[0][mi][1], bfr[ni][1], acc[mi][2 + ni], 0, 0, 0);              \
      }                                                                        \
    PH_BOT                                                                     \
    /* ---- phase 4: quadrant (mh1, nh1); stage Bnh0(k+2); counted vmcnt */    \
    if ((k) + 2 < NT) { STAGE_B(0, p, (k) + 2); }                              \
    __builtin_amdgcn_sched_barrier(0);                                         \
    __builtin_amdgcn_s_barrier();                                              \
    __builtin_amdgcn_s_setprio(1);                                             \
    _Pragma("unroll") for (int mi = 0; mi < 4; ++mi)                           \
      _Pragma("unroll") for (int ni = 0; ni < 2; ++ni) {                       \
        acc[4 + mi][2 + ni] = __builtin_amdgcn_mfma_f32_16x16x32_bf16(         \
            afr[1][mi][0], bfr[ni][0], acc[4 + mi][2 + ni], 0, 0, 0);          \
        acc[4 + mi][2 + ni] = __builtin_amdgcn_mfma_f32_16x16x32_bf16(         \
            afr[1][mi][1], bfr[ni][1], acc[4 + mi][2 + ni], 0, 0, 0);          \
      }                                                                        \
    __builtin_amdgcn_s_setprio(0);                                             \
    __builtin_amdgcn_sched_barrier(0);                                         \
    if ((k) + 2 < NT) {                                                        \
      asm volatile("s_waitcnt vmcnt(6)" ::: "memory");                         \
    } else {                                                                   \
      asm volatile("s_waitcnt vmcnt(0)" ::: "memory");                         \
    }                                                                          \
    __builtin_amdgcn_sched_barrier(0);                                         \
    __builtin_amdgcn_s_barrier();                                              \
  }

  for (int kk = 0; kk < NT / 2; ++kk) {
    int k0 = 2 * kk;
    GROUP(k0, 0)
    GROUP(k0 + 1, 1)
  }
#undef GROUP
#undef STAGE_A
#undef STAGE_B
#undef RD_A
#undef RD_B

  // epilogue: C-write (col = lane&15, row = (lane>>4)*4 + j)
  #pragma unroll
  for (int n = 0; n < 4; ++n) {
    int gc = n0 + wn * 64 + n * 16 + lr;
    float bv = bias[e * ND + gc];
    #pragma unroll
    for (int m = 0; m < 8; ++m) {
      int gr0 = r0 + wm * 128 + m * 16 + lk8 * 4;
      #pragma unroll
      for (int j = 0; j < 4; ++j) {
        float v = acc[m][n][j] + bv;
        if (RELU) v = fmaxf(v, 0.f);
        out[((size_t)(e * CAP + gr0 + j)) * ND + gc] = f2bf(v);
      }
    }
  }
}

// ---------------- decode: y[s] = g1*valid1*Y[d1] + g2*valid2*Y[d2] ----------------
__global__ __launch_bounds__(256) void decode_kernel(
    const unsigned short* __restrict__ Y, const int* __restrict__ dest,
    const float* __restrict__ gn, float* __restrict__ y) {
  int t = blockIdx.x * 4 + (threadIdx.x >> 6);
  int m0 = (threadIdx.x & 63) * 8;
  int d0 = dest[t * 2 + 0], d1 = dest[t * 2 + 1];
  float g0 = gn[t * 2 + 0], g1 = gn[t * 2 + 1];
  float o[8];
  #pragma unroll
  for (int j = 0; j < 8; ++j) o[j] = 0.f;
  if (d0 >= 0) {
    short8 v = *reinterpret_cast<const short8*>(&Y[(size_t)d0 * M_DIM + m0]);
    #pragma unroll
    for (int j = 0; j < 8; ++j) o[j] += g0 * bf2f((unsigned short)v[j]);
  }
  if (d1 >= 0) {
    short8 v = *reinterpret_cast<const short8*>(&Y[(size_t)d1 * M_DIM + m0]);
    #pragma unroll
    for (int j = 0; j < 8; ++j) o[j] += g1 * bf2f((unsigned short)v[j]);
  }
  float4 o0 = {o[0], o[1], o[2], o[3]};
  float4 o1 = {o[4], o[5], o[6], o[7]};
  *reinterpret_cast<float4*>(&y[(size_t)t * M_DIM + m0]) = o0;
  *reinterpret_cast<float4*>(&y[(size_t)t * M_DIM + m0 + 4]) = o1;
}

// ---------------- aux loss ----------------
__global__ void loss_kernel(const float* __restrict__ me_part,
                            const int* __restrict__ ce_part,
                            float* __restrict__ out) {
  int e = threadIdx.x;  // 64 threads
  float sme = 0.f, sce = 0.f;
  for (int b = 0; b < S_TOK / 16; ++b) {
    sme += me_part[b * 64 + e];
    sce += (float)ce_part[b * 64 + e];
  }
  float p = sme * sce;
  #pragma unroll
  for (int off = 32; off; off >>= 1) p += __shfl_xor(p, off);
  if (e == 0) out[0] = p * ((float)E_NUM / ((float)S_TOK * (float)S_TOK));
}

extern "C" void kernel_launch(void* const* d_in, const int* in_sizes, int n_in,
                              void* d_out, int out_size, void* d_ws, size_t ws_size,
                              hipStream_t stream) {
  const float* x     = (const float*)d_in[0];
  const float* wg    = (const float*)d_in[1];
  const float* fc1_w = (const float*)d_in[2];
  const float* fc1_b = (const float*)d_in[3];
  const float* fc2_w = (const float*)d_in[4];
  const float* fc2_b = (const float*)d_in[5];
  float* y = (float*)d_out;
  float* loss_out = y + (size_t)S_TOK * M_DIM;

  char* ws = (char*)d_ws;
  size_t off = 0;
  auto alloc = [&](size_t bytes) {
    char* p = ws + off;
    off += (bytes + 255) & ~(size_t)255;
    return p;
  };
  unsigned short* wT1 = (unsigned short*)alloc((size_t)E_NUM * V_DIM * M_DIM * 2);  // 128 MB
  unsigned short* wT2 = (unsigned short*)alloc((size_t)E_NUM * M_DIM * V_DIM * 2);  // 128 MB
  unsigned short* H   = (unsigned short*)alloc((size_t)E_NUM * CAP * V_DIM * 2);    // 256 MB
  unsigned short* xbf = (unsigned short*)alloc((size_t)S_TOK * M_DIM * 2);          // 32 MB
  int*   topk     = (int*)alloc((size_t)S_TOK * 2 * 4);
  float* gatesn   = (float*)alloc((size_t)S_TOK * 2 * 4);
  int*   dest     = (int*)alloc((size_t)S_TOK * 2 * 4);
  int*   slot_map = (int*)alloc((size_t)E_NUM * CAP * 4);
  float* me_part  = (float*)alloc((size_t)(S_TOK / 16) * 64 * 4);
  int*   ce_part  = (int*)alloc((size_t)(S_TOK / 16) * 64 * 4);
  // Y aliases wT1 (wT1 dead after gemm1; gemm2 writes Y, reads wT2+H)
  unsigned short* Y = wT1;

  (void)hipMemsetAsync(slot_map, 0xFF, (size_t)E_NUM * CAP * 4, stream);

  convert_x_kernel<<<S_TOK * M_DIM / 4 / 256, 256, 0, stream>>>(x, xbf);
  // fc1_w [E][M][V] -> wT1 [E][V][M]
  transpose_convert<<<dim3(V_DIM / 32, M_DIM / 32, E_NUM), 256, 0, stream>>>(fc1_w, wT1, M_DIM, V_DIM);
  // fc2_w [E][V][M] -> wT2 [E][M][V]
  transpose_convert<<<dim3(M_DIM / 32, V_DIM / 32, E_NUM), 256, 0, stream>>>(fc2_w, wT2, V_DIM, M_DIM);

  gating_kernel<<<S_TOK / 16, 256, 0, stream>>>(x, wg, topk, gatesn, me_part, ce_part);
  rank_kernel<<<E_NUM, 256, 0, stream>>>(topk, dest, slot_map);

  // H = relu(gather(x) @ fc1 + b1):  [E*CAP x 512] @ [512 x 2048]
  gemm8_kernel<512, 2048, 8, 4, true, true>
      <<<E_NUM * 8 * 4, 512, 0, stream>>>(xbf, wT1, fc1_b, slot_map, H);
  // Y = H @ fc2 + b2:  [E*CAP x 2048] @ [2048 x 512]
  gemm8_kernel<2048, 512, 2, 4, false, false>
      <<<E_NUM * 2 * 4, 512, 0, stream>>>(H, wT2, fc2_b, slot_map, Y);

  decode_kernel<<<S_TOK / 4, 256, 0, stream>>>(Y, dest, gatesn, y);
  loss_kernel<<<1, 64, 0, stream>>>(me_part, ce_part, loss_out);
}

// Round 4
// 775.786 us; speedup vs baseline: 1.3894x; 1.2750x over previous
//
#include <hip/hip_runtime.h>
#include <hip/hip_bf16.h>
#include <stdint.h>

#define S_TOK 32768
#define M_DIM 512
#define E_NUM 64
#define V_DIM 2048
#define CAP   1024

typedef __attribute__((ext_vector_type(8))) short short8;
typedef __attribute__((ext_vector_type(4))) float f32x4;

__device__ __forceinline__ unsigned short f2bf(float f) {
  unsigned int u = __float_as_uint(f);
  unsigned int r = (u + 0x7fffu + ((u >> 16) & 1u)) >> 16;
  return (unsigned short)r;
}
__device__ __forceinline__ float bf2f(unsigned short h) {
  return __uint_as_float(((unsigned int)h) << 16);
}

__device__ __forceinline__ void gload16(const void* g, void* lds) {
  __builtin_amdgcn_global_load_lds(
      (const __attribute__((address_space(1))) void*)g,
      (__attribute__((address_space(3))) void*)lds, 16, 0, 0);
}

// ------------- weight transpose + convert: [b][R][Cc] f32 -> [b][Cc][R] bf16 -------------
__global__ __launch_bounds__(256) void transpose_convert(const float* __restrict__ in,
                                                         unsigned short* __restrict__ out,
                                                         int R, int Cc) {
  __shared__ float tile[32][33];
  int b = blockIdx.z;
  const float* ip = in + (size_t)b * R * Cc;
  unsigned short* op = out + (size_t)b * R * Cc;
  int c0 = blockIdx.x * 32, r0 = blockIdx.y * 32;
  int tx = threadIdx.x & 31, ty = threadIdx.x >> 5;  // ty: 0..7
  #pragma unroll
  for (int j = 0; j < 32; j += 8)
    tile[ty + j][tx] = ip[(size_t)(r0 + ty + j) * Cc + c0 + tx];
  __syncthreads();
  int tid = threadIdx.x;
  #pragma unroll
  for (int j = 0; j < 32; j += 16) {
    int c = (tid >> 4) + j;       // col within tile 0..31
    int r2 = (tid & 15) * 2;      // row pair
    ushort2 o;
    o.x = f2bf(tile[r2][c]);
    o.y = f2bf(tile[r2 + 1][c]);
    *reinterpret_cast<ushort2*>(&op[(size_t)(c0 + c) * R + r0 + r2]) = o;
  }
}

// ---------------- gating: logits, softmax, top-2, partial me/ce, x->bf16 ----------------
__global__ __launch_bounds__(256) void gating_kernel(
    const float* __restrict__ x, const float* __restrict__ wg,
    int* __restrict__ topk, float* __restrict__ gates_n,
    float* __restrict__ me_part, int* __restrict__ ce_part,
    unsigned short* __restrict__ xbf) {
  __shared__ float4 xs4[16 * 128];
  __shared__ float mered[4][64];
  __shared__ int cered[4][64];
  int tid = threadIdx.x;
  int l = tid & 63, w = tid >> 6;
  int tb = blockIdx.x * 16;
  const float4* xg4 = reinterpret_cast<const float4*>(x) + (size_t)tb * 128;
  ushort4* xb4 = reinterpret_cast<ushort4*>(xbf) + (size_t)tb * 128;
  #pragma unroll
  for (int i = 0; i < 8; ++i) {
    float4 v = xg4[i * 256 + tid];
    xs4[i * 256 + tid] = v;
    ushort4 o;
    o.x = f2bf(v.x); o.y = f2bf(v.y); o.z = f2bf(v.z); o.w = f2bf(v.w);
    xb4[i * 256 + tid] = o;   // fused x -> bf16 (replaces convert_x kernel)
  }
  __syncthreads();

  const float4* wg4 = reinterpret_cast<const float4*>(wg) + (size_t)l * 128;
  float acc[4] = {0.f, 0.f, 0.f, 0.f};
  for (int i = 0; i < 128; ++i) {
    float4 wv = wg4[i];
    #pragma unroll
    for (int t = 0; t < 4; ++t) {
      float4 xv = xs4[(w * 4 + t) * 128 + i];
      acc[t] += xv.x * wv.x; acc[t] += xv.y * wv.y;
      acc[t] += xv.z * wv.z; acc[t] += xv.w * wv.w;
    }
  }

  float melocal = 0.f;
  int celocal = 0;
  for (int t = 0; t < 4; ++t) {
    float v = acc[t];
    float bv = v; int bi = l;
    #pragma unroll
    for (int off = 32; off; off >>= 1) {
      float ov = __shfl_xor(bv, off);
      int oi = __shfl_xor(bi, off);
      if (ov > bv || (ov == bv && oi < bi)) { bv = ov; bi = oi; }
    }
    float v2 = (l == bi) ? -INFINITY : v;
    float bv2 = v2; int bi2 = l;
    #pragma unroll
    for (int off = 32; off; off >>= 1) {
      float ov = __shfl_xor(bv2, off);
      int oi = __shfl_xor(bi2, off);
      if (ov > bv2 || (ov == bv2 && oi < bi2)) { bv2 = ov; bi2 = oi; }
    }
    float ex = expf(v - bv);
    float s = ex;
    #pragma unroll
    for (int off = 32; off; off >>= 1) s += __shfl_xor(s, off);
    melocal += ex / s;
    if (l == bi) celocal += 1;
    if (l == 0) {
      int sidx = tb + w * 4 + t;
      topk[sidx * 2 + 0] = bi;
      topk[sidx * 2 + 1] = bi2;
      float g1 = 1.0f / s;
      float g2 = expf(bv2 - bv) / s;
      float denom = fmaxf(g1 + g2, 1.1920929e-07f);
      gates_n[sidx * 2 + 0] = g1 / denom;
      gates_n[sidx * 2 + 1] = g2 / denom;
    }
  }
  mered[w][l] = melocal;
  cered[w][l] = celocal;
  __syncthreads();
  if (tid < 64) {
    me_part[blockIdx.x * 64 + tid] =
        mered[0][tid] + mered[1][tid] + mered[2][tid] + mered[3][tid];
    ce_part[blockIdx.x * 64 + tid] =
        cered[0][tid] + cered[1][tid] + cered[2][tid] + cered[3][tid];
  }
}

// ---------------- capacity ranking: two-pass scan, no inner barriers ----------------
__global__ __launch_bounds__(256) void rank_kernel(const int* __restrict__ topk,
                                                   int* __restrict__ dest,
                                                   int* __restrict__ slot_map) {
  int e = blockIdx.x;
  int tid = threadIdx.x;
  int l = tid & 63, w = tid >> 6;
  const int2* tk = reinterpret_cast<const int2*>(topk);
  int base = tid * 128;
  // pass A: per-thread counts
  int c0 = 0, c1 = 0;
  for (int j = 0; j < 128; ++j) {
    int2 p = tk[base + j];
    c0 += (p.x == e); c1 += (p.y == e);
  }
  // wave inclusive scan
  int i0 = c0, i1 = c1;
  #pragma unroll
  for (int off = 1; off < 64; off <<= 1) {
    int t0 = __shfl_up(i0, off);
    int t1 = __shfl_up(i1, off);
    if (l >= off) { i0 += t0; i1 += t1; }
  }
  __shared__ int ws0[4], ws1[4], wo0[4], wo1[4], tot0s;
  if (l == 63) { ws0[w] = i0; ws1[w] = i1; }
  __syncthreads();
  if (tid == 0) {
    int a = 0, b = 0;
    #pragma unroll
    for (int j = 0; j < 4; ++j) { wo0[j] = a; a += ws0[j]; wo1[j] = b; b += ws1[j]; }
    tot0s = a;  // total uncapped top-1 count -> base offset for k=1
  }
  __syncthreads();
  int loc0 = wo0[w] + i0 - c0;
  int loc1 = tot0s + wo1[w] + i1 - c1;
  // pass B: assign
  for (int j = 0; j < 128; ++j) {
    int s = base + j;
    int2 p = tk[s];
    if (p.x == e) {
      int d = (loc0 < CAP) ? e * CAP + loc0 : -1;
      dest[s * 2] = d;
      if (d >= 0) slot_map[d] = s;
      loc0++;
    }
    if (p.y == e) {
      int d = (loc1 < CAP) ? e * CAP + loc1 : -1;
      dest[s * 2 + 1] = d;
      if (d >= 0) slot_map[d] = s;
      loc1++;
    }
  }
}

// =================== 256x256 8-phase MFMA GEMM (T2+T3+T4+T5) ===================
// A: row-major [rows][KD] bf16 (GATHER: rows via slot_map)
// BT: [E][ND][KD] bf16; out: [E*CAP][ND] bf16 = act(A@B + bias)
// 8 waves (2M x 4N), per-wave 128x64 out, BK=64, dbuf LDS 128 KiB, XOR swizzle.
// Epilogue stages C through LDS (union with stage buffers) for coalesced stores.
#define PH_TOP                                                                 \
  __builtin_amdgcn_sched_barrier(0);                                           \
  __builtin_amdgcn_s_barrier();                                                \
  asm volatile("s_waitcnt lgkmcnt(0)" ::: "memory");                           \
  __builtin_amdgcn_sched_barrier(0);                                           \
  __builtin_amdgcn_s_setprio(1);
#define PH_BOT                                                                 \
  __builtin_amdgcn_s_setprio(0);                                               \
  __builtin_amdgcn_sched_barrier(0);                                           \
  __builtin_amdgcn_s_barrier();

struct SmemGemm {
  union {
    struct {
      unsigned short A[2][256 * 64];
      unsigned short B[2][256 * 64];
    } st;
    unsigned short C[256 * 258];  // epilogue staging (132096 B total block LDS)
  };
};

template <int KD, int ND, int NBX, int NBY, bool GATHER, bool RELU>
__global__ __launch_bounds__(512, 2) void gemm8_kernel(
    const unsigned short* __restrict__ A,
    const unsigned short* __restrict__ BT,
    const float* __restrict__ bias,
    const int* __restrict__ slot_map,
    unsigned short* __restrict__ out) {
  constexpr int NT = KD / 64;  // K-tiles
  __shared__ SmemGemm sm;

  const int tid = threadIdx.x;
  const int l = tid & 63;
  const int w = tid >> 6;       // 0..7
  const int wm = w >> 2;        // 0..1
  const int wn = w & 3;         // 0..3
  const int lr = l & 15;
  const int lk8 = l >> 4;       // 0..3

  // XCD-chunked bijective block swizzle (nwg % 8 == 0)
  const int nwg = E_NUM * NBX * NBY;
  const int cpx = nwg >> 3;
  int lid = ((int)blockIdx.x % 8) * cpx + (int)blockIdx.x / 8;
  const int e = lid / (NBX * NBY);
  int rem = lid % (NBX * NBY);
  const int n0 = (rem / NBY) * 256;
  const int r0 = (rem % NBY) * 256;

  // stage swizzle: LDS group (l&7) at row r holds global colgroup (l&7)^(r&7)
  const int cg8 = (((l & 7) ^ (l >> 3)) * 8);

  uint32_t offA[2][2], offB[2][2], ldsA[2][2], ldsB[2][2];
  #pragma unroll
  for (int sel = 0; sel < 2; ++sel) {
    #pragma unroll
    for (int i = 0; i < 2; ++i) {
      int lr128 = i * 64 + w * 8 + (l >> 3);
      int ar = ((lr128 >> 6) * 128) + sel * 64 + (lr128 & 63);
      int br = ((lr128 >> 5) * 64) + sel * 32 + (lr128 & 31);
      ldsA[sel][i] = ar * 64 + (l & 7) * 8;
      ldsB[sel][i] = br * 64 + (l & 7) * 8;
      int arow;
      if (GATHER) {
        int s = slot_map[e * CAP + r0 + ar];
        if (s < 0) s = 0;  // unfilled slot: any valid row; output never read
        arow = s;
      } else {
        arow = e * CAP + r0 + ar;
      }
      offA[sel][i] = (uint32_t)arow * KD + cg8;
      offB[sel][i] = (uint32_t)(n0 + br) * KD + cg8;
    }
  }
  const unsigned short* Bexp = BT + (size_t)e * ND * KD;

#define STAGE_A(sel, p, kt)                                                    \
  do {                                                                         \
    gload16(A + offA[sel][0] + (kt) * 64, &sm.st.A[p][ldsA[sel][0]]);          \
    gload16(A + offA[sel][1] + (kt) * 64, &sm.st.A[p][ldsA[sel][1]]);          \
  } while (0)
#define STAGE_B(sel, p, kt)                                                    \
  do {                                                                         \
    gload16(Bexp + offB[sel][0] + (kt) * 64, &sm.st.B[p][ldsB[sel][0]]);       \
    gload16(Bexp + offB[sel][1] + (kt) * 64, &sm.st.B[p][ldsB[sel][1]]);       \
  } while (0)

  const int sg0 = ((0 + lk8) ^ (lr & 7)) * 8;
  const int sg1 = ((4 + lk8) ^ (lr & 7)) * 8;
#define RD_A(p, mh, mi, ks)                                                    \
  (*reinterpret_cast<const short8*>(                                           \
      &sm.st.A[p][(wm * 128 + (mh) * 64 + (mi) * 16 + lr) * 64 + ((ks) ? sg1 : sg0)]))
#define RD_B(p, nh, ni, ks)                                                    \
  (*reinterpret_cast<const short8*>(                                           \
      &sm.st.B[p][(wn * 64 + (nh) * 32 + (ni) * 16 + lr) * 64 + ((ks) ? sg1 : sg0)]))

  short8 afr[2][4][2];  // [mh][mi][ks]
  short8 bfr[2][2];     // [ni][ks], current nh
  f32x4 acc[8][4];
  f32x4 zero = {0.f, 0.f, 0.f, 0.f};
  #pragma unroll
  for (int m = 0; m < 8; ++m)
    #pragma unroll
    for (int n = 0; n < 4; ++n) acc[m][n] = zero;

  // prologue: tile0 complete + tile1 {Amh0, Amh1, Bnh0}  (14 vmem ops)
  STAGE_A(0, 0, 0); STAGE_A(1, 0, 0); STAGE_B(0, 0, 0); STAGE_B(1, 0, 0);
  STAGE_A(0, 1, 1); STAGE_A(1, 1, 1); STAGE_B(0, 1, 1);
  asm volatile("s_waitcnt vmcnt(6)" ::: "memory");  // tile0's 8 ops complete
  __builtin_amdgcn_sched_barrier(0);
  __builtin_amdgcn_s_barrier();

#define GROUP(k, p)                                                            \
  {                                                                            \
    /* ---- phase 1: quadrant (mh0, nh0); stage Bnh1(k+1) -> dbuf[p^1] */      \
    _Pragma("unroll") for (int mi = 0; mi < 4; ++mi) {                         \
      afr[0][mi][0] = RD_A(p, 0, mi, 0);                                       \
      afr[0][mi][1] = RD_A(p, 0, mi, 1);                                       \
    }                                                                          \
    _Pragma("unroll") for (int ni = 0; ni < 2; ++ni) {                         \
      bfr[ni][0] = RD_B(p, 0, ni, 0);                                          \
      bfr[ni][1] = RD_B(p, 0, ni, 1);                                          \
    }                                                                          \
    if ((k) + 1 < NT) { STAGE_B(1, (p) ^ 1, (k) + 1); }                        \
    PH_TOP                                                                     \
    _Pragma("unroll") for (int mi = 0; mi < 4; ++mi)                           \
      _Pragma("unroll") for (int ni = 0; ni < 2; ++ni) {                       \
        acc[mi][ni] = __builtin_amdgcn_mfma_f32_16x16x32_bf16(                 \
            afr[0][mi][0], bfr[ni][0], acc[mi][ni], 0, 0, 0);                  \
        acc[mi][ni] = __builtin_amdgcn_mfma_f32_16x16x32_bf16(                 \
            afr[0][mi][1], bfr[ni][1], acc[mi][ni], 0, 0, 0);                  \
      }                                                                        \
    PH_BOT                                                                     \
    /* ---- phase 2: quadrant (mh1, nh0); stage Amh0(k+2) -> dbuf[p] */        \
    _Pragma("unroll") for (int mi = 0; mi < 4; ++mi) {                         \
      afr[1][mi][0] = RD_A(p, 1, mi, 0);                                       \
      afr[1][mi][1] = RD_A(p, 1, mi, 1);                                       \
    }                                                                          \
    if ((k) + 2 < NT) { STAGE_A(0, p, (k) + 2); }                              \
    PH_TOP                                                                     \
    _Pragma("unroll") for (int mi = 0; mi < 4; ++mi)                           \
      _Pragma("unroll") for (int ni = 0; ni < 2; ++ni) {                       \
        acc[4 + mi][ni] = __builtin_amdgcn_mfma_f32_16x16x32_bf16(             \
            afr[1][mi][0], bfr[ni][0], acc[4 + mi][ni], 0, 0, 0);              \
        acc[4 + mi][ni] = __builtin_amdgcn_mfma_f32_16x16x32_bf16(             \
            afr[1][mi][1], bfr[ni][1], acc[4 + mi][ni], 0, 0, 0);              \
      }                                                                        \
    PH_BOT                                                                     \
    /* ---- phase 3: quadrant (mh0, nh1); stage Amh1(k+2) -> dbuf[p] */        \
    _Pragma("unroll") for (int ni = 0; ni < 2; ++ni) {                         \
      bfr[ni][0] = RD_B(p, 1, ni, 0);                                          \
      bfr[ni][1] = RD_B(p, 1, ni, 1);                                          \
    }                                                                          \
    if ((k) + 2 < NT) { STAGE_A(1, p, (k) + 2); }                              \
    PH_TOP                                                                     \
    _Pragma("unroll") for (int mi = 0; mi < 4; ++mi)                           \
      _Pragma("unroll") for (int ni = 0; ni < 2; ++ni) {                       \
        acc[mi][2 + ni] = __builtin_amdgcn_mfma_f32_16x16x32_bf16(             \
            afr[0][mi][0], bfr[ni][0], acc[mi][2 + ni], 0, 0, 0);              \
        acc[mi][2 + ni] = __builtin_amdgcn_mfma_f32_16x16x32_bf16(             \
            afr[0][mi][1], bfr[ni][1], acc[mi][2 + ni], 0, 0, 0);              \
      }                                                                        \
    PH_BOT                                                                     \
    /* ---- phase 4: quadrant (mh1, nh1); stage Bnh0(k+2); counted vmcnt */    \
    if ((k) + 2 < NT) { STAGE_B(0, p, (k) + 2); }                              \
    __builtin_amdgcn_sched_barrier(0);                                         \
    __builtin_amdgcn_s_barrier();                                              \
    __builtin_amdgcn_s_setprio(1);                                             \
    _Pragma("unroll") for (int mi = 0; mi < 4; ++mi)                           \
      _Pragma("unroll") for (int ni = 0; ni < 2; ++ni) {                       \
        acc[4 + mi][2 + ni] = __builtin_amdgcn_mfma_f32_16x16x32_bf16(         \
            afr[1][mi][0], bfr[ni][0], acc[4 + mi][2 + ni], 0, 0, 0);          \
        acc[4 + mi][2 + ni] = __builtin_amdgcn_mfma_f32_16x16x32_bf16(         \
            afr[1][mi][1], bfr[ni][1], acc[4 + mi][2 + ni], 0, 0, 0);          \
      }                                                                        \
    __builtin_amdgcn_s_setprio(0);                                             \
    __builtin_amdgcn_sched_barrier(0);                                         \
    if ((k) + 2 < NT) {                                                        \
      asm volatile("s_waitcnt vmcnt(6)" ::: "memory");                         \
    } else {                                                                   \
      asm volatile("s_waitcnt vmcnt(0)" ::: "memory");                         \
    }                                                                          \
    __builtin_amdgcn_sched_barrier(0);                                         \
    __builtin_amdgcn_s_barrier();                                              \
  }

  for (int kk = 0; kk < NT / 2; ++kk) {
    int k0 = 2 * kk;
    GROUP(k0, 0)
    GROUP(k0 + 1, 1)
  }
#undef GROUP
#undef STAGE_A
#undef STAGE_B
#undef RD_A
#undef RD_B

  // ---- epilogue: acc -> LDS (bias+relu+bf16), then coalesced global stores ----
  #pragma unroll
  for (int n = 0; n < 4; ++n) {
    int gcl = wn * 64 + n * 16 + lr;  // col within 256-tile
    float bv = bias[e * ND + n0 + gcl];
    #pragma unroll
    for (int m = 0; m < 8; ++m) {
      int trow = wm * 128 + m * 16 + lk8 * 4;
      #pragma unroll
      for (int j = 0; j < 4; ++j) {
        float v = acc[m][n][j] + bv;
        if (RELU) v = fmaxf(v, 0.f);
        sm.C[(trow + j) * 258 + gcl] = f2bf(v);
      }
    }
  }
  __syncthreads();
  #pragma unroll
  for (int i = 0; i < 16; ++i) {
    int chunk = i * 512 + tid;        // 8192 chunks of 8 ushort
    int row = chunk >> 5;
    int c8 = chunk & 31;
    short8 v = *reinterpret_cast<const short8*>(&sm.C[row * 258 + c8 * 8]);
    *reinterpret_cast<short8*>(
        &out[((size_t)(e * CAP + r0 + row)) * ND + n0 + c8 * 8]) = v;
  }
}

// ---------------- decode: y[s] = g1*valid1*Y[d1] + g2*valid2*Y[d2] ----------------
__global__ __launch_bounds__(256) void decode_kernel(
    const unsigned short* __restrict__ Y, const int* __restrict__ dest,
    const float* __restrict__ gn, float* __restrict__ y) {
  int t = blockIdx.x * 4 + (threadIdx.x >> 6);
  int m0 = (threadIdx.x & 63) * 8;
  int d0 = dest[t * 2 + 0], d1 = dest[t * 2 + 1];
  float g0 = gn[t * 2 + 0], g1 = gn[t * 2 + 1];
  float o[8];
  #pragma unroll
  for (int j = 0; j < 8; ++j) o[j] = 0.f;
  if (d0 >= 0) {
    short8 v = *reinterpret_cast<const short8*>(&Y[(size_t)d0 * M_DIM + m0]);
    #pragma unroll
    for (int j = 0; j < 8; ++j) o[j] += g0 * bf2f((unsigned short)v[j]);
  }
  if (d1 >= 0) {
    short8 v = *reinterpret_cast<const short8*>(&Y[(size_t)d1 * M_DIM + m0]);
    #pragma unroll
    for (int j = 0; j < 8; ++j) o[j] += g1 * bf2f((unsigned short)v[j]);
  }
  float4 o0 = {o[0], o[1], o[2], o[3]};
  float4 o1 = {o[4], o[5], o[6], o[7]};
  *reinterpret_cast<float4*>(&y[(size_t)t * M_DIM + m0]) = o0;
  *reinterpret_cast<float4*>(&y[(size_t)t * M_DIM + m0 + 4]) = o1;
}

// ---------------- aux loss: parallel 2-level reduction ----------------
__global__ __launch_bounds__(1024) void loss_kernel(const float* __restrict__ me_part,
                                                    const int* __restrict__ ce_part,
                                                    float* __restrict__ out) {
  int tid = threadIdx.x;
  int e = tid & 63, ch = tid >> 6;  // 16 chunks of 128 blocks
  float sme = 0.f, sce = 0.f;
  for (int j = 0; j < 128; ++j) {
    int idx = (ch * 128 + j) * 64 + e;
    sme += me_part[idx];
    sce += (float)ce_part[idx];
  }
  __shared__ float redm[16][64];
  __shared__ float redc[16][64];
  redm[ch][e] = sme;
  redc[ch][e] = sce;
  __syncthreads();
  if (tid < 64) {
    float m = 0.f, c = 0.f;
    #pragma unroll
    for (int k = 0; k < 16; ++k) { m += redm[k][tid]; c += redc[k][tid]; }
    float p = m * c;
    #pragma unroll
    for (int off = 32; off; off >>= 1) p += __shfl_xor(p, off);
    if (tid == 0) out[0] = p * ((float)E_NUM / ((float)S_TOK * (float)S_TOK));
  }
}

extern "C" void kernel_launch(void* const* d_in, const int* in_sizes, int n_in,
                              void* d_out, int out_size, void* d_ws, size_t ws_size,
                              hipStream_t stream) {
  const float* x     = (const float*)d_in[0];
  const float* wg    = (const float*)d_in[1];
  const float* fc1_w = (const float*)d_in[2];
  const float* fc1_b = (const float*)d_in[3];
  const float* fc2_w = (const float*)d_in[4];
  const float* fc2_b = (const float*)d_in[5];
  float* y = (float*)d_out;
  float* loss_out = y + (size_t)S_TOK * M_DIM;

  char* ws = (char*)d_ws;
  size_t off = 0;
  auto alloc = [&](size_t bytes) {
    char* p = ws + off;
    off += (bytes + 255) & ~(size_t)255;
    return p;
  };
  unsigned short* wT1 = (unsigned short*)alloc((size_t)E_NUM * V_DIM * M_DIM * 2);  // 128 MB
  unsigned short* wT2 = (unsigned short*)alloc((size_t)E_NUM * M_DIM * V_DIM * 2);  // 128 MB
  unsigned short* H   = (unsigned short*)alloc((size_t)E_NUM * CAP * V_DIM * 2);    // 256 MB
  unsigned short* xbf = (unsigned short*)alloc((size_t)S_TOK * M_DIM * 2);          // 32 MB
  int*   topk     = (int*)alloc((size_t)S_TOK * 2 * 4);
  float* gatesn   = (float*)alloc((size_t)S_TOK * 2 * 4);
  int*   dest     = (int*)alloc((size_t)S_TOK * 2 * 4);
  int*   slot_map = (int*)alloc((size_t)E_NUM * CAP * 4);
  float* me_part  = (float*)alloc((size_t)(S_TOK / 16) * 64 * 4);
  int*   ce_part  = (int*)alloc((size_t)(S_TOK / 16) * 64 * 4);
  // Y aliases wT1 (wT1 dead after gemm1; gemm2 writes Y, reads wT2+H)
  unsigned short* Y = wT1;

  (void)hipMemsetAsync(slot_map, 0xFF, (size_t)E_NUM * CAP * 4, stream);

  // fc1_w [E][M][V] -> wT1 [E][V][M]
  transpose_convert<<<dim3(V_DIM / 32, M_DIM / 32, E_NUM), 256, 0, stream>>>(fc1_w, wT1, M_DIM, V_DIM);
  // fc2_w [E][V][M] -> wT2 [E][M][V]
  transpose_convert<<<dim3(M_DIM / 32, V_DIM / 32, E_NUM), 256, 0, stream>>>(fc2_w, wT2, V_DIM, M_DIM);

  gating_kernel<<<S_TOK / 16, 256, 0, stream>>>(x, wg, topk, gatesn, me_part, ce_part, xbf);
  rank_kernel<<<E_NUM, 256, 0, stream>>>(topk, dest, slot_map);

  // H = relu(gather(x) @ fc1 + b1):  [E*CAP x 512] @ [512 x 2048]
  gemm8_kernel<512, 2048, 8, 4, true, true>
      <<<E_NUM * 8 * 4, 512, 0, stream>>>(xbf, wT1, fc1_b, slot_map, H);
  // Y = H @ fc2 + b2:  [E*CAP x 2048] @ [2048 x 512]
  gemm8_kernel<2048, 512, 2, 4, false, false>
      <<<E_NUM * 2 * 4, 512, 0, stream>>>(H, wT2, fc2_b, slot_map, Y);

  decode_kernel<<<S_TOK / 4, 256, 0, stream>>>(Y, dest, gatesn, y);
  loss_kernel<<<1, 1024, 0, stream>>>(me_part, ce_part, loss_out);
}